// Round 1
// baseline (266.326 us; speedup 1.0000x reference)
//
#include <hip/hip_runtime.h>
#include <math.h>

#define B_ 8
#define T_ 4096
#define M_ 1024
#define TT 64          // rows per block tile; T_/TT * B_ = 512 blocks
#define EPSF 1e-6f

// 16-tap causal bump convolution along T + per-channel softplus gate.
// out[b,t,m] = gate[m] * (1/S_t) * sum_{d=0}^{15} w[d] * x[b,t-d,m]
// w[d] = exp(1 - 1/(1 - u^2 + eps)), u = min(d/15, 1-eps); w[15] underflows to 0.
// S_t = sum_{d=0}^{min(t,15)} w[d]  (partial renorm only affects t<15).
__global__ __launch_bounds__(256) void bump_conv_kernel(
    const float* __restrict__ x,
    const float* __restrict__ gate_raw,
    float* __restrict__ out) {
  const int tiles = T_ / TT;
  const int tile = blockIdx.x % tiles;
  const int b    = blockIdx.x / tiles;
  const int t0   = tile * TT;            // multiple of 16 -> ring slot = s
  const int m    = threadIdx.x * 4;      // 256 threads * float4 = M_

  // --- taps (per-thread, 16 expf, negligible) ---
  float w[16];
  float S = 0.0f;
#pragma unroll
  for (int d = 0; d < 16; ++d) {
    float u = fminf((float)d * (1.0f / 15.0f), 1.0f - EPSF);
    float den = 1.0f - u * u + EPSF;
    w[d] = expf(1.0f - 1.0f / den);      // d=15 -> expf(-3.3e5) == 0.0f
    S += w[d];
  }
  const float rsS = 1.0f / fmaxf(S, EPSF);

  // --- per-channel gate: softplus(gate_raw) ---
  const float4 graw = *(const float4*)(gate_raw + m);
  float4 g;
  g.x = fmaxf(graw.x, 0.0f) + log1pf(expf(-fabsf(graw.x)));
  g.y = fmaxf(graw.y, 0.0f) + log1pf(expf(-fabsf(graw.y)));
  g.z = fmaxf(graw.z, 0.0f) + log1pf(expf(-fabsf(graw.z)));
  g.w = fmaxf(graw.w, 0.0f) + log1pf(expf(-fabsf(graw.w)));

  const float* xb = x   + (size_t)b * T_ * M_ + m;
  float*       ob = out + (size_t)b * T_ * M_ + m;

  // --- ring buffer: slot for row t is (t & 15) ---
  float4 r[16];
  r[0] = make_float4(0.f, 0.f, 0.f, 0.f);
#pragma unroll
  for (int k = 1; k <= 15; ++k) {        // halo rows t0-15 .. t0-1 -> slots 1..15
    const int t = t0 - 16 + k;
    r[k] = (t >= 0) ? *(const float4*)(xb + (size_t)t * M_)
                    : make_float4(0.f, 0.f, 0.f, 0.f);
  }
  float4 nxt = *(const float4*)(xb + (size_t)t0 * M_);  // prefetch row t0

  for (int c = 0; c < TT / 16; ++c) {
#pragma unroll
    for (int s = 0; s < 16; ++s) {
      const int t = t0 + c * 16 + s;
      const float4 cur = nxt;
      const int tn = t + 1;
      if (tn < T_) nxt = *(const float4*)(xb + (size_t)tn * M_);  // prefetch
      r[s] = cur;  // (t & 15) == s since t0 % 16 == 0

      float ax = 0.f, ay = 0.f, az = 0.f, aw = 0.f;
#pragma unroll
      for (int d = 0; d < 16; ++d) {
        const float4 v = r[(s - d + 16) & 15];  // compile-time index
        const float wd = w[d];
        ax = fmaf(wd, v.x, ax);
        ay = fmaf(wd, v.y, ay);
        az = fmaf(wd, v.z, az);
        aw = fmaf(wd, v.w, aw);
      }

      float sc = rsS;
      if (t < 15) {                      // wave-uniform; only tile 0, chunk 0
        float p = 0.0f;
#pragma unroll
        for (int d = 0; d < 16; ++d) p += (d <= t) ? w[d] : 0.0f;
        sc = 1.0f / fmaxf(p, EPSF);
      }

      float4 o;
      o.x = ax * sc * g.x;
      o.y = ay * sc * g.y;
      o.z = az * sc * g.z;
      o.w = aw * sc * g.w;
      *(float4*)(ob + (size_t)t * M_) = o;
    }
  }
}

extern "C" void kernel_launch(void* const* d_in, const int* in_sizes, int n_in,
                              void* d_out, int out_size, void* d_ws, size_t ws_size,
                              hipStream_t stream) {
  const float* x         = (const float*)d_in[0];
  // d_in[1] = mask (T,T): redundant (taps already causal) -- intentionally unread.
  const float* gate_raw  = (const float*)d_in[2];
  float*       out       = (float*)d_out;

  dim3 grid(B_ * (T_ / TT));   // 512 blocks
  dim3 block(256);
  bump_conv_kernel<<<grid, block, 0, stream>>>(x, gate_raw, out);
}